// Round 10
// baseline (243.034 us; speedup 1.0000x reference)
//
#include <hip/hip_runtime.h>
#include <stdint.h>

// DynamicFc R16: R13 minus waves_per_eu = R15 + restored bv rings.
//  R15 post-mortem: deleting the bvr/bvc rings let the full-unrolled 32-iter
//  B/C loops HOIST all 32 pgb bias loads (~128 regs each phase) -> blew the
//  128-VGPR allocation -> FETCH 82->179MB, WRITE 42->236MB scratch round-trip,
//  mega 78->144us. Allocator pins 128 VGPR regardless of launch_bounds(512,2)
//  (seen R11/R12/R15) => every phase must fit ~120 live regs and all loads in
//  full-unrolled loops must be explicitly ring-buffered.
//  This version: ring-4 af + ring-4 bvr/bvc (R12/R13-style, 4 live bv max),
//  B wave=(mh,lq) 4-partial hred[4][32][33], C wave-owned full-m reduction
//  (barriers 8->2, gred deleted), R15's lean D (no w2 dbuf). No waves_per_eu
//  (sole suspect in R13's container failure).
//  Register audit: A 72 | B 120 | C 120 | D 96  (<=120 target).
// B=8192, F=1024, LOW=128, MID=32. p1: j=l*32+m (j<4096), p2: j=4096+m*128+l.
// Fragment-major images: chunk(T,ks)[lane][8] = W[T*16+(lane&15)][ks*32+(lane>>4)*8..+8]
// Tripwires: WRITE ~33-42MB, FETCH ~82MB, VGPR ~128.

typedef __attribute__((ext_vector_type(8))) short bf16x8;
typedef __attribute__((ext_vector_type(4))) float f32x4;

#define MFMA(a, b, c) __builtin_amdgcn_mfma_f32_16x16x32_bf16((a), (b), (c), 0, 0, 0)

__device__ __forceinline__ ushort f2bf(float x) {
    union { float f; uint32_t u; } v; v.f = x;
    return (ushort)((v.u + 0x7FFFu + ((v.u >> 16) & 1u)) >> 16);
}
__device__ __forceinline__ ushort4 f2bf4(float4 v) {
    ushort4 o; o.x = f2bf(v.x); o.y = f2bf(v.y); o.z = f2bf(v.z); o.w = f2bf(v.w); return o;
}
__device__ __forceinline__ float bf2f(ushort u) {
    union { uint32_t i; float f; } v; v.i = ((uint32_t)u) << 16; return v.f;
}

// ---------------- K0: convert + fragment-major re-layout (verified) ----------------
__global__ __launch_bounds__(256) void k0_convert(
    const float* __restrict__ pgw, const float* __restrict__ wf,
    const float* __restrict__ wpf, const float* __restrict__ w2,
    ushort* __restrict__ pg_img, ushort* __restrict__ w_img, ushort* __restrict__ w2_img)
{
    int cid = blockIdx.x * 256 + threadIdx.x;   // 704*256 = 180224
    const float* src; ushort* dst;
    if (cid < 131072) {                                  // pg: 512*4*64
        int lane = cid & 63, ks = (cid >> 6) & 3, T = cid >> 8;
        int j = T * 16 + (lane & 15), k = ks * 32 + (lane >> 4) * 8;
        src = pgw + (size_t)j * 128 + k;
        dst = pg_img + (size_t)cid * 8;
    } else if (cid < 163840) {                           // wf/wpf: 2*8*32*64
        int c = cid - 131072;
        int lane = c & 63, ks = (c >> 6) & 31, lt = (c >> 11) & 7, mat = c >> 14;
        int l = lt * 16 + (lane & 15), k = ks * 32 + (lane >> 4) * 8;
        src = (mat ? wpf : wf) + (size_t)l * 1024 + k;
        dst = w_img + (size_t)c * 8;
    } else {                                             // w2: 64*4*64
        int c = cid - 163840;
        int lane = c & 63, ks = (c >> 6) & 3, nt = c >> 8;
        int n = nt * 16 + (lane & 15), k = ks * 32 + (lane >> 4) * 8;
        src = w2 + (size_t)n * 128 + k;
        dst = w2_img + (size_t)c * 8;
    }
    float4 a = ((const float4*)src)[0], b = ((const float4*)src)[1];
    ((ushort4*)dst)[0] = f2bf4(a);
    ((ushort4*)dst)[1] = f2bf4(b);
}

// ---------------- MEGA: one block = 32 samples end-to-end, 8 waves ----------------
// grid 256 x 512 threads; 1 block/CU, 2 waves/SIMD.
__global__ __launch_bounds__(512, 2) void mega(
    const float* __restrict__ f, const float* __restrict__ pf,
    const ushort* __restrict__ w_img, const float* __restrict__ bfb,
    const float* __restrict__ bpfb, const ushort* __restrict__ pg_img,
    const float* __restrict__ pgb, const ushort* __restrict__ w2_img,
    const float* __restrict__ b2, float* __restrict__ out)
{
    __shared__ __align__(16) char smem[62464];
    // region0 (0..36864), phase-reused:
    //  A: As [32][520]us = 33280 | Tr [32][136]us (after As dead)
    //  B: hred [4][32][33]f = 16896 | hl [32][32]f @16896
    //  C: gLDS [128][33]f = 16896 @0 (hred dead; disjoint from hl)
    //  D: Ls [32][288]f = 36864 @0
    ushort* As    = (ushort*)smem;
    ushort* Tr    = (ushort*)smem;
    float*  hred  = (float*)smem;               // [4][32*33]
    float*  hl    = (float*)(smem + 16896);     // [32][32]
    float*  gLDS  = (float*)smem;               // [128][33]
    float*  Ls    = (float*)smem;               // [32][288]
    ushort* flowT = (ushort*)(smem + 36864);    // [128][36] bf16 = 9216 B
    ushort* pfrag = (ushort*)(smem + 46080);    // 8 chunks * 512 = 8192 B
    ushort* gfrag = (ushort*)(smem + 54272);    // 8 chunks * 512 = 8192 B

    const int tid = threadIdx.x;
    const int lane = tid & 63, wid = tid >> 6;   // wid 0..7
    const int q = lane >> 4, r15 = lane & 15;
    const int b0 = blockIdx.x * 32;

    // ================= Phase A: f_low / pf_low projections (stage-pipelined) ========
    {
        float4 vbuf[8];
#pragma unroll
        for (int rr = 0; rr < 8; rr++) {
            int row = rr * 4 + (tid >> 7);
            vbuf[rr] = *(const float4*)(f + (size_t)(b0 + row) * 1024 + (tid & 127) * 4);
        }
        f32x4 c[2];
        float bias_v = 0.f;
#pragma unroll
        for (int s = 0; s < 4; s++) {            // (mat,kh) = (0,0)(0,1)(1,0)(1,1)
            const int mat = s >> 1, kh = s & 1;
            if (kh == 0) {
                c[0] = (f32x4){0.f, 0.f, 0.f, 0.f};
                c[1] = (f32x4){0.f, 0.f, 0.f, 0.f};
                bias_v = (mat ? bpfb : bfb)[wid * 16 + r15];
            }
            __syncthreads();                     // prior As readers done
#pragma unroll
            for (int rr = 0; rr < 8; rr++) {
                int row = rr * 4 + (tid >> 7);
                *(ushort4*)(As + row * 520 + (tid & 127) * 4) = f2bf4(vbuf[rr]);
            }
            __syncthreads();
            if (s < 3) {                         // issue NEXT stage loads (hide HBM)
                const int sn = s + 1, matn = sn >> 1, khn = sn & 1;
                const float* srcn = matn ? pf : f;
#pragma unroll
                for (int rr = 0; rr < 8; rr++) {
                    int row = rr * 4 + (tid >> 7);
                    vbuf[rr] = *(const float4*)(srcn + (size_t)(b0 + row) * 1024 + khn * 512 + (tid & 127) * 4);
                }
            }
            const ushort* wb = w_img + (size_t)mat * 131072 + ((size_t)wid * 32 + kh * 16) * 512;
            bf16x8 wfr[4];
#pragma unroll
            for (int p = 0; p < 4; p++) wfr[p] = *(const bf16x8*)(wb + (size_t)p * 512 + lane * 8);
#pragma unroll
            for (int ks = 0; ks < 16; ks++) {    // full unroll, ring-4
                const int cur = ks & 3;
                bf16x8 a0 = *(const bf16x8*)(As + (size_t)r15 * 520 + ks * 32 + q * 8);
                bf16x8 a1 = *(const bf16x8*)(As + (size_t)(16 + r15) * 520 + ks * 32 + q * 8);
                c[0] = MFMA(a0, wfr[cur], c[0]);
                c[1] = MFMA(a1, wfr[cur], c[1]);
                if (ks + 4 < 16)
                    wfr[cur] = *(const bf16x8*)(wb + (size_t)(ks + 4) * 512 + lane * 8);
            }
            // C: row = b_local (mt*16 + q*4 + r), col = l (wid*16 + r15)
            if (s == 1) {                        // mat0 epilogue -> flowT (disjoint)
                int l = wid * 16 + r15;
#pragma unroll
                for (int mt = 0; mt < 2; mt++)
#pragma unroll
                    for (int r = 0; r < 4; r++)
                        flowT[l * 36 + mt * 16 + q * 4 + r] = f2bf(c[mt][r] + bias_v);
            }
            if (s == 3) {                        // mat1 epilogue -> Tr -> pfrag
                __syncthreads();                 // all As reads done before Tr overwrite
                int l = wid * 16 + r15;
#pragma unroll
                for (int mt = 0; mt < 2; mt++)
#pragma unroll
                    for (int r = 0; r < 4; r++)
                        Tr[(mt * 16 + q * 4 + r) * 136 + l] = f2bf(c[mt][r] + bias_v);
                __syncthreads();
                // emit pfrag: one chunk per wave (chunkid = wid = bt*4 + ks2)
                int bt = wid >> 2, ks2 = wid & 3;
                int k0 = ks2 * 32 + (lane >> 4) * 8;
                uint4 tv = *(const uint4*)(Tr + (size_t)(bt * 16 + (lane & 15)) * 136 + k0);
                *(uint4*)(pfrag + (size_t)wid * 512 + lane * 8) = tv;
            }
        }
    }
    __syncthreads();   // pfrag/flowT visible to all waves

    // ================= Phase B: h — wave=(mh,lq), 32-tile ring-4 af+bv, 4 partials ===
    bf16x8 bfr[2][4];  // pf_low fragments, held through B and C
#pragma unroll
    for (int ct = 0; ct < 2; ct++)
#pragma unroll
        for (int ks = 0; ks < 4; ks++)
            bfr[ct][ks] = *(const bf16x8*)(pfrag + (size_t)(ct * 4 + ks) * 512 + lane * 8);

    {
        const int mh = wid & 1, lq = wid >> 1;   // m-half, l-quarter
        f32x4 hacc[2];                           // [ct]; h[m=mh*16+q*4+r][b=ct*16+r15]
        hacc[0] = (f32x4){0.f, 0.f, 0.f, 0.f};
        hacc[1] = (f32x4){0.f, 0.f, 0.f, 0.f};

        bf16x8 af[4][4];
        f32x4 bvr[4];
#pragma unroll
        for (int t = 0; t < 4; t++) {            // preload: p1 tile T = l*2 + mh
            const int T = (lq * 32 + t) * 2 + mh;
            const ushort* ap = pg_img + (size_t)T * 2048;
#pragma unroll
            for (int ks = 0; ks < 4; ks++)
                af[t][ks] = *(const bf16x8*)(ap + ks * 512 + lane * 8);
            bvr[t] = *(const f32x4*)(pgb + (size_t)T * 16 + q * 4);
        }
#pragma unroll
        for (int t = 0; t < 32; t++) {           // full unroll, cross-tile ring-4
            const int cur = t & 3;
            const int l = lq * 32 + t;
            f32x4 bv = bvr[cur];
#pragma unroll
            for (int ct = 0; ct < 2; ct++) {
                f32x4 cc = (f32x4){0.f, 0.f, 0.f, 0.f};
#pragma unroll
                for (int ks = 0; ks < 4; ks++) cc = MFMA(af[cur][ks], bfr[ct][ks], cc);
                float s = bf2f(flowT[l * 36 + ct * 16 + r15]);
#pragma unroll
                for (int r = 0; r < 4; r++) hacc[ct][r] += s * (cc[r] + bv[r]);
            }
            if (t + 4 < 32) {
                const int Tn = (l + 4) * 2 + mh;
                const ushort* ap = pg_img + (size_t)Tn * 2048;
#pragma unroll
                for (int ks = 0; ks < 4; ks++)
                    af[cur][ks] = *(const bf16x8*)(ap + ks * 512 + lane * 8);
                bvr[cur] = *(const f32x4*)(pgb + (size_t)Tn * 16 + q * 4);
            }
        }
#pragma unroll
        for (int ct = 0; ct < 2; ct++)
#pragma unroll
            for (int r = 0; r < 4; r++)
                hred[lq * 1056 + (mh * 16 + q * 4 + r) * 33 + ct * 16 + r15] = hacc[ct][r];
    }
    __syncthreads();
    {   // 4-partial reduce + relu -> hl [32 m][32 b]; 512 threads, 2 floats each
        int m = tid >> 4, bc = (tid & 15) * 2;
        float s0 = 0.f, s1 = 0.f;
#pragma unroll
        for (int w = 0; w < 4; w++) {
            s0 += hred[w * 1056 + m * 33 + bc];
            s1 += hred[w * 1056 + m * 33 + bc + 1];
        }
        hl[m * 32 + bc]     = fmaxf(s0, 0.f);
        hl[m * 32 + bc + 1] = fmaxf(s1, 0.f);
    }
    __syncthreads();

    // ================= Phase C: g — wave owns l-tile wid, ALL 32 m, ring-4 ==========
    {
        f32x4 gacc[2];                           // [ct]; g[l=wid*16+q*4+r][b=ct*16+r15]
        gacc[0] = (f32x4){0.f, 0.f, 0.f, 0.f};
        gacc[1] = (f32x4){0.f, 0.f, 0.f, 0.f};

        bf16x8 afc[4][4];
        f32x4 bvc[4];
#pragma unroll
        for (int t = 0; t < 4; t++) {            // preload: p2 tile T = 256 + m*8 + wid
            const ushort* ap = pg_img + (size_t)(256 + t * 8 + wid) * 2048;
#pragma unroll
            for (int ks = 0; ks < 4; ks++)
                afc[t][ks] = *(const bf16x8*)(ap + ks * 512 + lane * 8);
            bvc[t] = *(const f32x4*)(pgb + 4096 + (size_t)t * 128 + wid * 16 + q * 4);
        }
#pragma unroll
        for (int m = 0; m < 32; m++) {           // full unroll, uninterrupted ring-4
            const int cur = m & 3;
            f32x4 bv = bvc[cur];
#pragma unroll
            for (int ct = 0; ct < 2; ct++) {
                f32x4 cc = (f32x4){0.f, 0.f, 0.f, 0.f};
#pragma unroll
                for (int ks = 0; ks < 4; ks++) cc = MFMA(afc[cur][ks], bfr[ct][ks], cc);
                float s = hl[m * 32 + ct * 16 + r15];   // same-addr across q: broadcast
#pragma unroll
                for (int r = 0; r < 4; r++) gacc[ct][r] += s * (cc[r] + bv[r]);
            }
            if (m + 4 < 32) {
                const int mn = m + 4;
                const ushort* ap = pg_img + (size_t)(256 + mn * 8 + wid) * 2048;
#pragma unroll
                for (int ks = 0; ks < 4; ks++)
                    afc[cur][ks] = *(const bf16x8*)(ap + ks * 512 + lane * 8);
                bvc[cur] = *(const f32x4*)(pgb + 4096 + (size_t)mn * 128 + wid * 16 + q * 4);
            }
        }
        // full m-sum done in-wave: write [16 l][32 b] patch to gLDS (pad 33)
#pragma unroll
        for (int ct = 0; ct < 2; ct++)
#pragma unroll
            for (int r = 0; r < 4; r++)
                gLDS[(size_t)(wid * 16 + q * 4 + r) * 33 + ct * 16 + r15] = gacc[ct][r];
    }
    __syncthreads();
    {   // emit gfrag: chunk wid = (bt = wid>>2, ksl = wid&3)
        const int bt = wid >> 2, ksl = wid & 3;
        const int bloc = bt * 16 + (lane & 15);
        const int l0 = ksl * 32 + (lane >> 4) * 8;
        ushort tmp[8];
#pragma unroll
        for (int e = 0; e < 8; e++)
            tmp[e] = f2bf(gLDS[(size_t)(l0 + e) * 33 + bloc]);
        ushort4 lo = {tmp[0], tmp[1], tmp[2], tmp[3]};
        ushort4 hi = {tmp[4], tmp[5], tmp[6], tmp[7]};
        ushort* dst = gfrag + (size_t)wid * 512 + lane * 8;
        ((ushort4*)dst)[0] = lo;
        ((ushort4*)dst)[1] = hi;
    }
    __syncthreads();

    // ================= Phase D: out = g@W2^T + b2 + f + pf (fa/pa prefetch) =========
    {
        bf16x8 afg[2][4];
#pragma unroll
        for (int mtl = 0; mtl < 2; mtl++)
#pragma unroll
            for (int ks = 0; ks < 4; ks++)
                afg[mtl][ks] = *(const bf16x8*)(gfrag + (size_t)(mtl * 4 + ks) * 512 + lane * 8);

#pragma unroll
        for (int nb = 0; nb < 4; nb++) {
            const int n0 = nb * 256;
            // early epilogue loads: land before the post-Ls barrier
            float4 fa[4], pa[4];
#pragma unroll
            for (int rr = 0; rr < 4; rr++) {
                const int b = b0 + wid * 4 + rr;
                const size_t gbase = (size_t)b * 1024 + n0 + lane * 4;
                fa[rr] = *(const float4*)(f + gbase);
                pa[rr] = *(const float4*)(pf + gbase);
            }
            float bias_v2[2];
#pragma unroll
            for (int nt = 0; nt < 2; nt++) bias_v2[nt] = b2[nb * 256 + wid * 32 + nt * 16 + r15];
            bf16x8 w2r[2][4];
#pragma unroll
            for (int nt = 0; nt < 2; nt++)
#pragma unroll
                for (int ks = 0; ks < 4; ks++)
                    w2r[nt][ks] = *(const bf16x8*)(w2_img + (size_t)((nb * 16 + wid * 2 + nt) * 4 + ks) * 512 + lane * 8);
#pragma unroll
            for (int nt = 0; nt < 2; nt++) {
#pragma unroll
                for (int mtl = 0; mtl < 2; mtl++) {
                    f32x4 cc = (f32x4){0.f, 0.f, 0.f, 0.f};
#pragma unroll
                    for (int ks = 0; ks < 4; ks++) cc = MFMA(afg[mtl][ks], w2r[nt][ks], cc);
                    const int nloc = wid * 32 + nt * 16 + r15;        // 0..255
                    const int chunk = nloc >> 5, within = nloc & 31;
#pragma unroll
                    for (int r = 0; r < 4; r++)
                        Ls[(size_t)(mtl * 16 + q * 4 + r) * 288 + chunk * 36 + within] = cc[r] + bias_v2[nt];
                }
            }
            __syncthreads();
            {   // wave-contiguous epilogue: wave w rows w*4..+4, lane i <-> n0+4i
                const float* ls = Ls + (size_t)(wid * 4) * 288 + (lane >> 3) * 36 + (lane & 7) * 4;
#pragma unroll
                for (int rr = 0; rr < 4; rr++) {
                    const int b = b0 + wid * 4 + rr;
                    const size_t gbase = (size_t)b * 1024 + n0 + lane * 4;
                    float4 lv = *(const float4*)(ls + rr * 288);
                    float4 o;
                    o.x = lv.x + fa[rr].x + pa[rr].x; o.y = lv.y + fa[rr].y + pa[rr].y;
                    o.z = lv.z + fa[rr].z + pa[rr].z; o.w = lv.w + fa[rr].w + pa[rr].w;
                    *(float4*)(out + gbase) = o;
                }
            }
            __syncthreads();   // Ls reuse protection for next nb
        }
    }
}

// ---------------- launch ----------------
extern "C" void kernel_launch(void* const* d_in, const int* in_sizes, int n_in,
                              void* d_out, int out_size, void* d_ws, size_t ws_size,
                              hipStream_t stream)
{
    const float* f    = (const float*)d_in[0];
    const float* pf   = (const float*)d_in[1];
    const float* wf   = (const float*)d_in[2];
    const float* bfb  = (const float*)d_in[3];
    const float* wpf  = (const float*)d_in[4];
    const float* bpfb = (const float*)d_in[5];
    const float* w2   = (const float*)d_in[6];
    const float* b2   = (const float*)d_in[7];
    const float* pgw  = (const float*)d_in[8];
    const float* pgb  = (const float*)d_in[9];

    char* ws = (char*)d_ws;
    ushort* pg_img = (ushort*)(ws + 0);          // 2 MB
    ushort* w_img  = (ushort*)(ws + 2097152);    // 512 KB
    ushort* w2_img = (ushort*)(ws + 2621440);    // 256 KB
    float*  out    = (float*)d_out;

    k0_convert<<<dim3(704), dim3(256), 0, stream>>>(pgw, wf, wpf, w2, pg_img, w_img, w2_img);
    mega<<<dim3(256), dim3(512), 0, stream>>>(f, pf, w_img, bfb, bpfb,
                                              pg_img, pgb, w2_img, b2, out);
}

// Round 11
// 171.896 us; speedup vs baseline: 1.4138x; 1.4138x over previous
//
#include <hip/hip_runtime.h>
#include <stdint.h>

// DynamicFc R17: verified-R12 phase bodies + bounded unroll windows.
//  R16 falsified the bias-hoist theory: restoring bv rings changed nothing
//  (FETCH 177 / WRITE 233 = R15). The spiller is the FLAT 32-iter fully
//  unrolled B/C loops (R15/R16-only construct): full unroll lets the
//  scheduler hoist ~32 LDS scalars + addresses across the whole region ->
//  live set >> 128-VGPR pin -> ~200MB scratch. R12's nested loops bounded
//  the window (only ~9MB leak).
//  This version = R12 exactly, except:
//   - B: outer jg loop '#pragma unroll 1' (ring idx: (jg*4+i)&3 == i, static)
//   - C: outer lg loop '#pragma unroll 1' (ring idx: (lg*8+ti)&3 == ti&3)
//   - D: lean single-buffer w2r (R15/R16-verified) + '#pragma unroll 1' on nb
//  A unchanged (stage-pipelined, verified). LDS layout = R12.
// B=8192, F=1024, LOW=128, MID=32. p1: j=l*32+m (j<4096), p2: j=4096+m*128+l.
// Fragment-major images: chunk(T,ks)[lane][8] = W[T*16+(lane&15)][ks*32+(lane>>4)*8..+8]
// Tripwires: WRITE ~33-36MB, FETCH ~80MB, VGPR ~128.

typedef __attribute__((ext_vector_type(8))) short bf16x8;
typedef __attribute__((ext_vector_type(4))) float f32x4;

#define MFMA(a, b, c) __builtin_amdgcn_mfma_f32_16x16x32_bf16((a), (b), (c), 0, 0, 0)

__device__ __forceinline__ ushort f2bf(float x) {
    union { float f; uint32_t u; } v; v.f = x;
    return (ushort)((v.u + 0x7FFFu + ((v.u >> 16) & 1u)) >> 16);
}
__device__ __forceinline__ ushort4 f2bf4(float4 v) {
    ushort4 o; o.x = f2bf(v.x); o.y = f2bf(v.y); o.z = f2bf(v.z); o.w = f2bf(v.w); return o;
}
__device__ __forceinline__ float bf2f(ushort u) {
    union { uint32_t i; float f; } v; v.i = ((uint32_t)u) << 16; return v.f;
}

// ---------------- K0: convert + fragment-major re-layout (verified) ----------------
__global__ __launch_bounds__(256) void k0_convert(
    const float* __restrict__ pgw, const float* __restrict__ wf,
    const float* __restrict__ wpf, const float* __restrict__ w2,
    ushort* __restrict__ pg_img, ushort* __restrict__ w_img, ushort* __restrict__ w2_img)
{
    int cid = blockIdx.x * 256 + threadIdx.x;   // 704*256 = 180224
    const float* src; ushort* dst;
    if (cid < 131072) {                                  // pg: 512*4*64
        int lane = cid & 63, ks = (cid >> 6) & 3, T = cid >> 8;
        int j = T * 16 + (lane & 15), k = ks * 32 + (lane >> 4) * 8;
        src = pgw + (size_t)j * 128 + k;
        dst = pg_img + (size_t)cid * 8;
    } else if (cid < 163840) {                           // wf/wpf: 2*8*32*64
        int c = cid - 131072;
        int lane = c & 63, ks = (c >> 6) & 31, lt = (c >> 11) & 7, mat = c >> 14;
        int l = lt * 16 + (lane & 15), k = ks * 32 + (lane >> 4) * 8;
        src = (mat ? wpf : wf) + (size_t)l * 1024 + k;
        dst = w_img + (size_t)c * 8;
    } else {                                             // w2: 64*4*64
        int c = cid - 163840;
        int lane = c & 63, ks = (c >> 6) & 3, nt = c >> 8;
        int n = nt * 16 + (lane & 15), k = ks * 32 + (lane >> 4) * 8;
        src = w2 + (size_t)n * 128 + k;
        dst = w2_img + (size_t)c * 8;
    }
    float4 a = ((const float4*)src)[0], b = ((const float4*)src)[1];
    ((ushort4*)dst)[0] = f2bf4(a);
    ((ushort4*)dst)[1] = f2bf4(b);
}

// ---------------- MEGA: one block = 32 samples end-to-end, 8 waves ----------------
// grid 256 x 512 threads; 1 block/CU, 2 waves/SIMD.
__global__ __launch_bounds__(512, 2) void mega(
    const float* __restrict__ f, const float* __restrict__ pf,
    const ushort* __restrict__ w_img, const float* __restrict__ bfb,
    const float* __restrict__ bpfb, const ushort* __restrict__ pg_img,
    const float* __restrict__ pgb, const ushort* __restrict__ w2_img,
    const float* __restrict__ b2, float* __restrict__ out)
{
    __shared__ __align__(16) char smem[62464];
    // region0 (0..36864): As 33280 | Tr 8704 | hred 32768 (+hl 4096 @32768) |
    //                     gred 32768 | Ls 36864  (phase-reused, R12 layout)
    ushort* As    = (ushort*)smem;              // [32][520]
    ushort* Tr    = (ushort*)smem;              // [32][136]
    float*  hred  = (float*)smem;               // [8][32][32]
    float*  hl    = (float*)(smem + 32768);     // [32][32]
    float*  gred  = (float*)smem;               // [8][32][32]
    float*  Ls    = (float*)smem;               // [32][288]
    ushort* flowT = (ushort*)(smem + 36864);    // [128][36] bf16 = 9216 B
    ushort* pfrag = (ushort*)(smem + 46080);    // 8 chunks * 512 = 8192 B
    ushort* gfrag = (ushort*)(smem + 54272);    // 8 chunks * 512 = 8192 B

    const int tid = threadIdx.x;
    const int lane = tid & 63, wid = tid >> 6;   // wid 0..7
    const int q = lane >> 4, r15 = lane & 15;
    const int b0 = blockIdx.x * 32;

    // ================= Phase A: f_low / pf_low projections (stage-pipelined) ========
    {
        float4 vbuf[8];
#pragma unroll
        for (int rr = 0; rr < 8; rr++) {
            int row = rr * 4 + (tid >> 7);
            vbuf[rr] = *(const float4*)(f + (size_t)(b0 + row) * 1024 + (tid & 127) * 4);
        }
        f32x4 c[2];
        float bias_v = 0.f;
#pragma unroll
        for (int s = 0; s < 4; s++) {            // (mat,kh) = (0,0)(0,1)(1,0)(1,1)
            const int mat = s >> 1, kh = s & 1;
            if (kh == 0) {
                c[0] = (f32x4){0.f, 0.f, 0.f, 0.f};
                c[1] = (f32x4){0.f, 0.f, 0.f, 0.f};
                bias_v = (mat ? bpfb : bfb)[wid * 16 + r15];
            }
            __syncthreads();                     // prior As readers done
#pragma unroll
            for (int rr = 0; rr < 8; rr++) {
                int row = rr * 4 + (tid >> 7);
                *(ushort4*)(As + row * 520 + (tid & 127) * 4) = f2bf4(vbuf[rr]);
            }
            __syncthreads();
            if (s < 3) {                         // issue NEXT stage loads (hide HBM)
                const int sn = s + 1, matn = sn >> 1, khn = sn & 1;
                const float* srcn = matn ? pf : f;
#pragma unroll
                for (int rr = 0; rr < 8; rr++) {
                    int row = rr * 4 + (tid >> 7);
                    vbuf[rr] = *(const float4*)(srcn + (size_t)(b0 + row) * 1024 + khn * 512 + (tid & 127) * 4);
                }
            }
            const ushort* wb = w_img + (size_t)mat * 131072 + ((size_t)wid * 32 + kh * 16) * 512;
            bf16x8 wfr[4];
#pragma unroll
            for (int p = 0; p < 4; p++) wfr[p] = *(const bf16x8*)(wb + (size_t)p * 512 + lane * 8);
#pragma unroll
            for (int ks = 0; ks < 16; ks++) {    // full unroll, ring-4
                const int cur = ks & 3;
                bf16x8 a0 = *(const bf16x8*)(As + (size_t)r15 * 520 + ks * 32 + q * 8);
                bf16x8 a1 = *(const bf16x8*)(As + (size_t)(16 + r15) * 520 + ks * 32 + q * 8);
                c[0] = MFMA(a0, wfr[cur], c[0]);
                c[1] = MFMA(a1, wfr[cur], c[1]);
                if (ks + 4 < 16)
                    wfr[cur] = *(const bf16x8*)(wb + (size_t)(ks + 4) * 512 + lane * 8);
            }
            // C: row = b_local (mt*16 + q*4 + r), col = l (wid*16 + r15)
            if (s == 1) {                        // mat0 epilogue -> flowT (disjoint)
                int l = wid * 16 + r15;
#pragma unroll
                for (int mt = 0; mt < 2; mt++)
#pragma unroll
                    for (int r = 0; r < 4; r++)
                        flowT[l * 36 + mt * 16 + q * 4 + r] = f2bf(c[mt][r] + bias_v);
            }
            if (s == 3) {                        // mat1 epilogue -> Tr -> pfrag
                __syncthreads();                 // all As reads done before Tr overwrite
                int l = wid * 16 + r15;
#pragma unroll
                for (int mt = 0; mt < 2; mt++)
#pragma unroll
                    for (int r = 0; r < 4; r++)
                        Tr[(mt * 16 + q * 4 + r) * 136 + l] = f2bf(c[mt][r] + bias_v);
                __syncthreads();
                // emit pfrag: one chunk per wave (chunkid = wid = bt*4 + ks2)
                int bt = wid >> 2, ks2 = wid & 3;
                int k0 = ks2 * 32 + (lane >> 4) * 8;
                uint4 tv = *(const uint4*)(Tr + (size_t)(bt * 16 + (lane & 15)) * 136 + k0);
                *(uint4*)(pfrag + (size_t)wid * 512 + lane * 8) = tv;
            }
        }
    }
    __syncthreads();   // pfrag/flowT visible to all waves

    // ================= Phase B: h partials — jg loop (unroll 1), ring-4 =============
    bf16x8 bfr[2][4];  // pf_low fragments, held through B and C
#pragma unroll
    for (int ct = 0; ct < 2; ct++)
#pragma unroll
        for (int ks = 0; ks < 4; ks++)
            bfr[ct][ks] = *(const bf16x8*)(pfrag + (size_t)(ct * 4 + ks) * 512 + lane * 8);

    f32x4 hacc[2][2];   // [m-half][ct]
    hacc[0][0] = hacc[0][1] = hacc[1][0] = hacc[1][1] = (f32x4){0.f, 0.f, 0.f, 0.f};

    {
        bf16x8 af[4][4];
        f32x4 bvr[4];
#pragma unroll
        for (int t = 0; t < 4; t++) {            // preload jg=0 tiles (i=t)
            const int tl = wid * 4 + t;
            const ushort* ap = pg_img + (size_t)tl * 2048;
#pragma unroll
            for (int ks = 0; ks < 4; ks++)
                af[t][ks] = *(const bf16x8*)(ap + ks * 512 + lane * 8);
            bvr[t] = *(const f32x4*)(pgb + (size_t)tl * 16 + q * 4);
        }
#pragma unroll 1
        for (int jg = 0; jg < 8; jg++) {         // BOUNDED window: no cross-jg hoist
#pragma unroll
            for (int i = 0; i < 4; i++) {        // ring idx (jg*4+i)&3 == i: static
                const int tl = wid * 4 + i;      // p1 tile index within jg (0..31)
                const int mh = i & 1;            // tl&1 (wid*4 even)
                const int l_loc = tl >> 1;
                f32x4 bv = bvr[i];
#pragma unroll
                for (int ct = 0; ct < 2; ct++) {
                    f32x4 cc = (f32x4){0.f, 0.f, 0.f, 0.f};
#pragma unroll
                    for (int ks = 0; ks < 4; ks++) cc = MFMA(af[i][ks], bfr[ct][ks], cc);
                    float s = bf2f(flowT[(jg * 16 + l_loc) * 36 + ct * 16 + r15]);
#pragma unroll
                    for (int r = 0; r < 4; r++) hacc[mh][ct][r] += s * (cc[r] + bv[r]);
                }
                if (jg < 7) {                    // reload tile i of jg+1 (ring dist 4)
                    const int tln = (jg + 1) * 32 + wid * 4 + i;
                    const ushort* ap = pg_img + (size_t)tln * 2048;
#pragma unroll
                    for (int ks = 0; ks < 4; ks++)
                        af[i][ks] = *(const bf16x8*)(ap + ks * 512 + lane * 8);
                    bvr[i] = *(const f32x4*)(pgb + (size_t)tln * 16 + q * 4);
                }
            }
        }
    }
#pragma unroll
    for (int mh = 0; mh < 2; mh++)
#pragma unroll
        for (int ct = 0; ct < 2; ct++)
#pragma unroll
            for (int r = 0; r < 4; r++)
                hred[wid * 1024 + (mh * 16 + q * 4 + r) * 32 + ct * 16 + r15] = hacc[mh][ct][r];
    __syncthreads();
    {   // 8-partial reduce + relu -> hl [32 m][32 b]; 512 threads, 2 floats each
        int m = tid >> 4, bc = (tid & 15) * 2;
        float s0 = 0.f, s1 = 0.f;
#pragma unroll
        for (int w = 0; w < 8; w++) {
            s0 += hred[w * 1024 + m * 32 + bc];
            s1 += hred[w * 1024 + m * 32 + bc + 1];
        }
        hl[m * 32 + bc]     = fmaxf(s0, 0.f);
        hl[m * 32 + bc + 1] = fmaxf(s1, 0.f);
    }
    __syncthreads();

    // ================= Phase C: g — lg loop (unroll 1), cross-lg ring-4 =============
    {
        bf16x8 afc[4][4];
        f32x4 bvc[4];
#pragma unroll
        for (int t = 0; t < 4; t++) {            // preload lg=0, ti=0..3
            const int m = wid + 8 * (t >> 1), lt = t & 1;
            const ushort* ap = pg_img + (size_t)(256 + m * 8 + lt) * 2048;
#pragma unroll
            for (int ks = 0; ks < 4; ks++)
                afc[t][ks] = *(const bf16x8*)(ap + ks * 512 + lane * 8);
            bvc[t] = *(const f32x4*)(pgb + 4096 + (size_t)m * 128 + lt * 16 + q * 4);
        }
#pragma unroll 1
        for (int lg = 0; lg < 4; lg++) {         // BOUNDED window: no cross-lg hoist
            f32x4 gacc[2][2];   // [lt][ct]
            gacc[0][0] = gacc[0][1] = gacc[1][0] = gacc[1][1] = (f32x4){0.f, 0.f, 0.f, 0.f};
#pragma unroll
            for (int ti = 0; ti < 8; ti++) {     // ring idx (lg*8+ti)&3 == ti&3: static
                const int cur = ti & 3;
                const int m = wid + 8 * (ti >> 1), lt = ti & 1;
                f32x4 bv = bvc[cur];
#pragma unroll
                for (int ct = 0; ct < 2; ct++) {
                    f32x4 cc = (f32x4){0.f, 0.f, 0.f, 0.f};
#pragma unroll
                    for (int ks = 0; ks < 4; ks++) cc = MFMA(afc[cur][ks], bfr[ct][ks], cc);
                    float s = hl[m * 32 + ct * 16 + r15];
#pragma unroll
                    for (int r = 0; r < 4; r++) gacc[lt][ct][r] += s * (cc[r] + bv[r]);
                }
                {   // reload 4 tiles ahead (crosses into lg+1 when ti>=4)
                    const int t = lg * 8 + ti;
                    if (t + 4 < 32) {
                        const int tn = t + 4, lgn = tn >> 3, tin = tn & 7;
                        const int mn = wid + 8 * (tin >> 1), ltn = tin & 1;
                        const ushort* ap = pg_img + (size_t)(256 + mn * 8 + lgn * 2 + ltn) * 2048;
#pragma unroll
                        for (int ks = 0; ks < 4; ks++)
                            afc[cur][ks] = *(const bf16x8*)(ap + ks * 512 + lane * 8);
                        bvc[cur] = *(const f32x4*)(pgb + 4096 + (size_t)mn * 128 + lgn * 32 + ltn * 16 + q * 4);
                    }
                }
            }
#pragma unroll
            for (int lt = 0; lt < 2; lt++)
#pragma unroll
                for (int ct = 0; ct < 2; ct++)
#pragma unroll
                    for (int r = 0; r < 4; r++)
                        gred[wid * 1024 + (lt * 16 + q * 4 + r) * 32 + ct * 16 + r15] = gacc[lt][ct][r];
            __syncthreads();
            if (tid < 128) {   // 8-partial reduce + emit gfrag chunk (bt, ks=lg)
                int bt = tid >> 6, ln = tid & 63;
                int b_loc = bt * 16 + (ln & 15);
                int l0 = (ln >> 4) * 8;
                ushort tmp[8];
#pragma unroll
                for (int e = 0; e < 8; e++) {
                    const float* gp = gred + (size_t)(l0 + e) * 32 + b_loc;
                    float s = 0.f;
#pragma unroll
                    for (int w = 0; w < 8; w++) s += gp[w * 1024];
                    tmp[e] = f2bf(s);
                }
                ushort4 lo = {tmp[0], tmp[1], tmp[2], tmp[3]};
                ushort4 hi = {tmp[4], tmp[5], tmp[6], tmp[7]};
                ushort* dst = gfrag + (size_t)(bt * 4 + lg) * 512 + ln * 8;
                ((ushort4*)dst)[0] = lo;
                ((ushort4*)dst)[1] = hi;
            }
            __syncthreads();   // gred reuse (and gfrag ready after last lg)
        }
    }

    // ================= Phase D: out (lean w2r, nb loop unroll 1) ====================
    {
        bf16x8 afg[2][4];
#pragma unroll
        for (int mtl = 0; mtl < 2; mtl++)
#pragma unroll
            for (int ks = 0; ks < 4; ks++)
                afg[mtl][ks] = *(const bf16x8*)(gfrag + (size_t)(mtl * 4 + ks) * 512 + lane * 8);

#pragma unroll 1
        for (int nb = 0; nb < 4; nb++) {         // BOUNDED window
            const int n0 = nb * 256;
            // early epilogue loads: land before the post-Ls barrier
            float4 fa[4], pa[4];
#pragma unroll
            for (int rr = 0; rr < 4; rr++) {
                const int b = b0 + wid * 4 + rr;
                const size_t gbase = (size_t)b * 1024 + n0 + lane * 4;
                fa[rr] = *(const float4*)(f + gbase);
                pa[rr] = *(const float4*)(pf + gbase);
            }
            float bias_v2[2];
#pragma unroll
            for (int nt = 0; nt < 2; nt++) bias_v2[nt] = b2[nb * 256 + wid * 32 + nt * 16 + r15];
            bf16x8 w2r[2][4];
#pragma unroll
            for (int nt = 0; nt < 2; nt++)
#pragma unroll
                for (int ks = 0; ks < 4; ks++)
                    w2r[nt][ks] = *(const bf16x8*)(w2_img + (size_t)((nb * 16 + wid * 2 + nt) * 4 + ks) * 512 + lane * 8);
#pragma unroll
            for (int nt = 0; nt < 2; nt++) {
#pragma unroll
                for (int mtl = 0; mtl < 2; mtl++) {
                    f32x4 cc = (f32x4){0.f, 0.f, 0.f, 0.f};
#pragma unroll
                    for (int ks = 0; ks < 4; ks++) cc = MFMA(afg[mtl][ks], w2r[nt][ks], cc);
                    const int nloc = wid * 32 + nt * 16 + r15;        // 0..255
                    const int chunk = nloc >> 5, within = nloc & 31;
#pragma unroll
                    for (int r = 0; r < 4; r++)
                        Ls[(size_t)(mtl * 16 + q * 4 + r) * 288 + chunk * 36 + within] = cc[r] + bias_v2[nt];
                }
            }
            __syncthreads();
            {   // wave-contiguous epilogue: wave w rows w*4..+4, lane i <-> n0+4i
                const float* ls = Ls + (size_t)(wid * 4) * 288 + (lane >> 3) * 36 + (lane & 7) * 4;
#pragma unroll
                for (int rr = 0; rr < 4; rr++) {
                    const int b = b0 + wid * 4 + rr;
                    const size_t gbase = (size_t)b * 1024 + n0 + lane * 4;
                    float4 lv = *(const float4*)(ls + rr * 288);
                    float4 o;
                    o.x = lv.x + fa[rr].x + pa[rr].x; o.y = lv.y + fa[rr].y + pa[rr].y;
                    o.z = lv.z + fa[rr].z + pa[rr].z; o.w = lv.w + fa[rr].w + pa[rr].w;
                    *(float4*)(out + gbase) = o;
                }
            }
            __syncthreads();   // Ls reuse protection for next nb
        }
    }
}

// ---------------- launch ----------------
extern "C" void kernel_launch(void* const* d_in, const int* in_sizes, int n_in,
                              void* d_out, int out_size, void* d_ws, size_t ws_size,
                              hipStream_t stream)
{
    const float* f    = (const float*)d_in[0];
    const float* pf   = (const float*)d_in[1];
    const float* wf   = (const float*)d_in[2];
    const float* bfb  = (const float*)d_in[3];
    const float* wpf  = (const float*)d_in[4];
    const float* bpfb = (const float*)d_in[5];
    const float* w2   = (const float*)d_in[6];
    const float* b2   = (const float*)d_in[7];
    const float* pgw  = (const float*)d_in[8];
    const float* pgb  = (const float*)d_in[9];

    char* ws = (char*)d_ws;
    ushort* pg_img = (ushort*)(ws + 0);          // 2 MB
    ushort* w_img  = (ushort*)(ws + 2097152);    // 512 KB
    ushort* w2_img = (ushort*)(ws + 2621440);    // 256 KB
    float*  out    = (float*)d_out;

    k0_convert<<<dim3(704), dim3(256), 0, stream>>>(pgw, wf, wpf, w2, pg_img, w_img, w2_img);
    mega<<<dim3(256), dim3(512), 0, stream>>>(f, pf, w_img, bfb, bpfb,
                                              pg_img, pgb, w2_img, b2, out);
}

// Round 12
// 164.884 us; speedup vs baseline: 1.4740x; 1.0425x over previous
//
#include <hip/hip_runtime.h>
#include <stdint.h>

// DynamicFc R18: R17 + R16's low-barrier B/C bodies under bounded windows.
//  R17 confirmed the spill model (WRITE 233->33MB, mega 141->71us): allocator
//  pins 128 VGPR; flat 32-iter unrolls hoist past it; '#pragma unroll 1' on
//  outer loops fixes it. Remaining: ~29 block barriers at 1 block/CU = dead
//  drain time (all pipes <20%).
//  This round ports R16's correctness-verified phase bodies (passed twice)
//  into the R17-proven bounded-window form:
//   B: wave=(mh=wid&1, lq=wid>>1): 32 p1 tiles as outer8 x inner4, ring-4
//      (cur=ti, static), 4-partial hred[4][32][33] (halves partial traffic)
//   C: wave owns l-tile wid, full m-sum over 32 p2 tiles in registers as
//      outer8 x inner4 ring-4 -> gred DELETED, barriers 8->2; gLDS [128][33]
//  A, D unchanged from R17 (verified).
//  Register audit: A 72 | B 120 | C 120 | D 96 (R17-B proved 128 clean).
// B=8192, F=1024, LOW=128, MID=32. p1: j=l*32+m (j<4096), p2: j=4096+m*128+l.
// Fragment-major images: chunk(T,ks)[lane][8] = W[T*16+(lane&15)][ks*32+(lane>>4)*8..+8]
// Tripwires: WRITE ~33MB, FETCH ~76MB, VGPR ~128.

typedef __attribute__((ext_vector_type(8))) short bf16x8;
typedef __attribute__((ext_vector_type(4))) float f32x4;

#define MFMA(a, b, c) __builtin_amdgcn_mfma_f32_16x16x32_bf16((a), (b), (c), 0, 0, 0)

__device__ __forceinline__ ushort f2bf(float x) {
    union { float f; uint32_t u; } v; v.f = x;
    return (ushort)((v.u + 0x7FFFu + ((v.u >> 16) & 1u)) >> 16);
}
__device__ __forceinline__ ushort4 f2bf4(float4 v) {
    ushort4 o; o.x = f2bf(v.x); o.y = f2bf(v.y); o.z = f2bf(v.z); o.w = f2bf(v.w); return o;
}
__device__ __forceinline__ float bf2f(ushort u) {
    union { uint32_t i; float f; } v; v.i = ((uint32_t)u) << 16; return v.f;
}

// ---------------- K0: convert + fragment-major re-layout (verified) ----------------
__global__ __launch_bounds__(256) void k0_convert(
    const float* __restrict__ pgw, const float* __restrict__ wf,
    const float* __restrict__ wpf, const float* __restrict__ w2,
    ushort* __restrict__ pg_img, ushort* __restrict__ w_img, ushort* __restrict__ w2_img)
{
    int cid = blockIdx.x * 256 + threadIdx.x;   // 704*256 = 180224
    const float* src; ushort* dst;
    if (cid < 131072) {                                  // pg: 512*4*64
        int lane = cid & 63, ks = (cid >> 6) & 3, T = cid >> 8;
        int j = T * 16 + (lane & 15), k = ks * 32 + (lane >> 4) * 8;
        src = pgw + (size_t)j * 128 + k;
        dst = pg_img + (size_t)cid * 8;
    } else if (cid < 163840) {                           // wf/wpf: 2*8*32*64
        int c = cid - 131072;
        int lane = c & 63, ks = (c >> 6) & 31, lt = (c >> 11) & 7, mat = c >> 14;
        int l = lt * 16 + (lane & 15), k = ks * 32 + (lane >> 4) * 8;
        src = (mat ? wpf : wf) + (size_t)l * 1024 + k;
        dst = w_img + (size_t)c * 8;
    } else {                                             // w2: 64*4*64
        int c = cid - 163840;
        int lane = c & 63, ks = (c >> 6) & 3, nt = c >> 8;
        int n = nt * 16 + (lane & 15), k = ks * 32 + (lane >> 4) * 8;
        src = w2 + (size_t)n * 128 + k;
        dst = w2_img + (size_t)c * 8;
    }
    float4 a = ((const float4*)src)[0], b = ((const float4*)src)[1];
    ((ushort4*)dst)[0] = f2bf4(a);
    ((ushort4*)dst)[1] = f2bf4(b);
}

// ---------------- MEGA: one block = 32 samples end-to-end, 8 waves ----------------
// grid 256 x 512 threads; 1 block/CU, 2 waves/SIMD.
__global__ __launch_bounds__(512, 2) void mega(
    const float* __restrict__ f, const float* __restrict__ pf,
    const ushort* __restrict__ w_img, const float* __restrict__ bfb,
    const float* __restrict__ bpfb, const ushort* __restrict__ pg_img,
    const float* __restrict__ pgb, const ushort* __restrict__ w2_img,
    const float* __restrict__ b2, float* __restrict__ out)
{
    __shared__ __align__(16) char smem[62464];
    // region0 (0..36864), phase-reused:
    //  A: As [32][520]us = 33280 | Tr [32][136]us (after As dead)
    //  B: hred [4][32][33]f = 16896 @0 | hl [32][32]f = 4096 @16896
    //  C: gLDS [128][33]f = 16896 @0 (hred dead; disjoint from hl)
    //  D: Ls [32][288]f = 36864 @0
    ushort* As    = (ushort*)smem;
    ushort* Tr    = (ushort*)smem;
    float*  hred  = (float*)smem;               // [4][32*33]
    float*  hl    = (float*)(smem + 16896);     // [32][32]
    float*  gLDS  = (float*)smem;               // [128][33]
    float*  Ls    = (float*)smem;               // [32][288]
    ushort* flowT = (ushort*)(smem + 36864);    // [128][36] bf16 = 9216 B
    ushort* pfrag = (ushort*)(smem + 46080);    // 8 chunks * 512 = 8192 B
    ushort* gfrag = (ushort*)(smem + 54272);    // 8 chunks * 512 = 8192 B

    const int tid = threadIdx.x;
    const int lane = tid & 63, wid = tid >> 6;   // wid 0..7
    const int q = lane >> 4, r15 = lane & 15;
    const int b0 = blockIdx.x * 32;

    // ================= Phase A: f_low / pf_low projections (stage-pipelined) ========
    {
        float4 vbuf[8];
#pragma unroll
        for (int rr = 0; rr < 8; rr++) {
            int row = rr * 4 + (tid >> 7);
            vbuf[rr] = *(const float4*)(f + (size_t)(b0 + row) * 1024 + (tid & 127) * 4);
        }
        f32x4 c[2];
        float bias_v = 0.f;
#pragma unroll
        for (int s = 0; s < 4; s++) {            // (mat,kh) = (0,0)(0,1)(1,0)(1,1)
            const int mat = s >> 1, kh = s & 1;
            if (kh == 0) {
                c[0] = (f32x4){0.f, 0.f, 0.f, 0.f};
                c[1] = (f32x4){0.f, 0.f, 0.f, 0.f};
                bias_v = (mat ? bpfb : bfb)[wid * 16 + r15];
            }
            __syncthreads();                     // prior As readers done
#pragma unroll
            for (int rr = 0; rr < 8; rr++) {
                int row = rr * 4 + (tid >> 7);
                *(ushort4*)(As + row * 520 + (tid & 127) * 4) = f2bf4(vbuf[rr]);
            }
            __syncthreads();
            if (s < 3) {                         // issue NEXT stage loads (hide HBM)
                const int sn = s + 1, matn = sn >> 1, khn = sn & 1;
                const float* srcn = matn ? pf : f;
#pragma unroll
                for (int rr = 0; rr < 8; rr++) {
                    int row = rr * 4 + (tid >> 7);
                    vbuf[rr] = *(const float4*)(srcn + (size_t)(b0 + row) * 1024 + khn * 512 + (tid & 127) * 4);
                }
            }
            const ushort* wb = w_img + (size_t)mat * 131072 + ((size_t)wid * 32 + kh * 16) * 512;
            bf16x8 wfr[4];
#pragma unroll
            for (int p = 0; p < 4; p++) wfr[p] = *(const bf16x8*)(wb + (size_t)p * 512 + lane * 8);
#pragma unroll
            for (int ks = 0; ks < 16; ks++) {    // full unroll, ring-4
                const int cur = ks & 3;
                bf16x8 a0 = *(const bf16x8*)(As + (size_t)r15 * 520 + ks * 32 + q * 8);
                bf16x8 a1 = *(const bf16x8*)(As + (size_t)(16 + r15) * 520 + ks * 32 + q * 8);
                c[0] = MFMA(a0, wfr[cur], c[0]);
                c[1] = MFMA(a1, wfr[cur], c[1]);
                if (ks + 4 < 16)
                    wfr[cur] = *(const bf16x8*)(wb + (size_t)(ks + 4) * 512 + lane * 8);
            }
            // C: row = b_local (mt*16 + q*4 + r), col = l (wid*16 + r15)
            if (s == 1) {                        // mat0 epilogue -> flowT (disjoint)
                int l = wid * 16 + r15;
#pragma unroll
                for (int mt = 0; mt < 2; mt++)
#pragma unroll
                    for (int r = 0; r < 4; r++)
                        flowT[l * 36 + mt * 16 + q * 4 + r] = f2bf(c[mt][r] + bias_v);
            }
            if (s == 3) {                        // mat1 epilogue -> Tr -> pfrag
                __syncthreads();                 // all As reads done before Tr overwrite
                int l = wid * 16 + r15;
#pragma unroll
                for (int mt = 0; mt < 2; mt++)
#pragma unroll
                    for (int r = 0; r < 4; r++)
                        Tr[(mt * 16 + q * 4 + r) * 136 + l] = f2bf(c[mt][r] + bias_v);
                __syncthreads();
                // emit pfrag: one chunk per wave (chunkid = wid = bt*4 + ks2)
                int bt = wid >> 2, ks2 = wid & 3;
                int k0 = ks2 * 32 + (lane >> 4) * 8;
                uint4 tv = *(const uint4*)(Tr + (size_t)(bt * 16 + (lane & 15)) * 136 + k0);
                *(uint4*)(pfrag + (size_t)wid * 512 + lane * 8) = tv;
            }
        }
    }
    __syncthreads();   // pfrag/flowT visible to all waves

    // ========= Phase B: h — wave=(mh,lq), outer8 x inner4 ring-4, 4 partials ========
    bf16x8 bfr[2][4];  // pf_low fragments, held through B and C
#pragma unroll
    for (int ct = 0; ct < 2; ct++)
#pragma unroll
        for (int ks = 0; ks < 4; ks++)
            bfr[ct][ks] = *(const bf16x8*)(pfrag + (size_t)(ct * 4 + ks) * 512 + lane * 8);

    {
        const int mh = wid & 1, lq = wid >> 1;   // m-half, l-quarter
        f32x4 hacc[2];                           // [ct]; h[m=mh*16+q*4+r][b=ct*16+r15]
        hacc[0] = (f32x4){0.f, 0.f, 0.f, 0.f};
        hacc[1] = (f32x4){0.f, 0.f, 0.f, 0.f};

        bf16x8 af[4][4];
        f32x4 bvr[4];
#pragma unroll
        for (int t = 0; t < 4; t++) {            // preload: p1 tile T = l*2 + mh
            const int T = (lq * 32 + t) * 2 + mh;
            const ushort* ap = pg_img + (size_t)T * 2048;
#pragma unroll
            for (int ks = 0; ks < 4; ks++)
                af[t][ks] = *(const bf16x8*)(ap + ks * 512 + lane * 8);
            bvr[t] = *(const f32x4*)(pgb + (size_t)T * 16 + q * 4);
        }
#pragma unroll 1
        for (int to = 0; to < 8; to++) {         // BOUNDED window
#pragma unroll
            for (int ti = 0; ti < 4; ti++) {     // ring idx (to*4+ti)&3 == ti: static
                const int t = to * 4 + ti;
                const int l = lq * 32 + t;
                f32x4 bv = bvr[ti];
#pragma unroll
                for (int ct = 0; ct < 2; ct++) {
                    f32x4 cc = (f32x4){0.f, 0.f, 0.f, 0.f};
#pragma unroll
                    for (int ks = 0; ks < 4; ks++) cc = MFMA(af[ti][ks], bfr[ct][ks], cc);
                    float s = bf2f(flowT[l * 36 + ct * 16 + r15]);
#pragma unroll
                    for (int r = 0; r < 4; r++) hacc[ct][r] += s * (cc[r] + bv[r]);
                }
                if (t + 4 < 32) {
                    const int Tn = (l + 4) * 2 + mh;
                    const ushort* ap = pg_img + (size_t)Tn * 2048;
#pragma unroll
                    for (int ks = 0; ks < 4; ks++)
                        af[ti][ks] = *(const bf16x8*)(ap + ks * 512 + lane * 8);
                    bvr[ti] = *(const f32x4*)(pgb + (size_t)Tn * 16 + q * 4);
                }
            }
        }
#pragma unroll
        for (int ct = 0; ct < 2; ct++)
#pragma unroll
            for (int r = 0; r < 4; r++)
                hred[lq * 1056 + (mh * 16 + q * 4 + r) * 33 + ct * 16 + r15] = hacc[ct][r];
    }
    __syncthreads();
    {   // 4-partial reduce + relu -> hl [32 m][32 b]; 512 threads, 2 floats each
        int m = tid >> 4, bc = (tid & 15) * 2;
        float s0 = 0.f, s1 = 0.f;
#pragma unroll
        for (int w = 0; w < 4; w++) {
            s0 += hred[w * 1056 + m * 33 + bc];
            s1 += hred[w * 1056 + m * 33 + bc + 1];
        }
        hl[m * 32 + bc]     = fmaxf(s0, 0.f);
        hl[m * 32 + bc + 1] = fmaxf(s1, 0.f);
    }
    __syncthreads();

    // ===== Phase C: g — wave owns l-tile wid, 32 m as outer8 x inner4 ring-4 ========
    {
        f32x4 gacc[2];                           // [ct]; g[l=wid*16+q*4+r][b=ct*16+r15]
        gacc[0] = (f32x4){0.f, 0.f, 0.f, 0.f};
        gacc[1] = (f32x4){0.f, 0.f, 0.f, 0.f};

        bf16x8 afc[4][4];
        f32x4 bvc[4];
#pragma unroll
        for (int t = 0; t < 4; t++) {            // preload: p2 tile T = 256 + m*8 + wid
            const ushort* ap = pg_img + (size_t)(256 + t * 8 + wid) * 2048;
#pragma unroll
            for (int ks = 0; ks < 4; ks++)
                afc[t][ks] = *(const bf16x8*)(ap + ks * 512 + lane * 8);
            bvc[t] = *(const f32x4*)(pgb + 4096 + (size_t)t * 128 + wid * 16 + q * 4);
        }
#pragma unroll 1
        for (int mo = 0; mo < 8; mo++) {         // BOUNDED window
#pragma unroll
            for (int mi = 0; mi < 4; mi++) {     // ring idx (mo*4+mi)&3 == mi: static
                const int m = mo * 4 + mi;
                f32x4 bv = bvc[mi];
#pragma unroll
                for (int ct = 0; ct < 2; ct++) {
                    f32x4 cc = (f32x4){0.f, 0.f, 0.f, 0.f};
#pragma unroll
                    for (int ks = 0; ks < 4; ks++) cc = MFMA(afc[mi][ks], bfr[ct][ks], cc);
                    float s = hl[m * 32 + ct * 16 + r15];   // broadcast read
#pragma unroll
                    for (int r = 0; r < 4; r++) gacc[ct][r] += s * (cc[r] + bv[r]);
                }
                if (m + 4 < 32) {
                    const int mn = m + 4;
                    const ushort* ap = pg_img + (size_t)(256 + mn * 8 + wid) * 2048;
#pragma unroll
                    for (int ks = 0; ks < 4; ks++)
                        afc[mi][ks] = *(const bf16x8*)(ap + ks * 512 + lane * 8);
                    bvc[mi] = *(const f32x4*)(pgb + 4096 + (size_t)mn * 128 + wid * 16 + q * 4);
                }
            }
        }
        // full m-sum done in-wave: write [16 l][32 b] patch to gLDS (pad 33)
#pragma unroll
        for (int ct = 0; ct < 2; ct++)
#pragma unroll
            for (int r = 0; r < 4; r++)
                gLDS[(size_t)(wid * 16 + q * 4 + r) * 33 + ct * 16 + r15] = gacc[ct][r];
    }
    __syncthreads();
    {   // emit gfrag: chunk wid = (bt = wid>>2, ksl = wid&3)
        const int bt = wid >> 2, ksl = wid & 3;
        const int bloc = bt * 16 + (lane & 15);
        const int l0 = ksl * 32 + (lane >> 4) * 8;
        ushort tmp[8];
#pragma unroll
        for (int e = 0; e < 8; e++)
            tmp[e] = f2bf(gLDS[(size_t)(l0 + e) * 33 + bloc]);
        ushort4 lo = {tmp[0], tmp[1], tmp[2], tmp[3]};
        ushort4 hi = {tmp[4], tmp[5], tmp[6], tmp[7]};
        ushort* dst = gfrag + (size_t)wid * 512 + lane * 8;
        ((ushort4*)dst)[0] = lo;
        ((ushort4*)dst)[1] = hi;
    }
    __syncthreads();

    // ================= Phase D: out (lean w2r, nb loop unroll 1) ====================
    {
        bf16x8 afg[2][4];
#pragma unroll
        for (int mtl = 0; mtl < 2; mtl++)
#pragma unroll
            for (int ks = 0; ks < 4; ks++)
                afg[mtl][ks] = *(const bf16x8*)(gfrag + (size_t)(mtl * 4 + ks) * 512 + lane * 8);

#pragma unroll 1
        for (int nb = 0; nb < 4; nb++) {         // BOUNDED window
            const int n0 = nb * 256;
            // early epilogue loads: land before the post-Ls barrier
            float4 fa[4], pa[4];
#pragma unroll
            for (int rr = 0; rr < 4; rr++) {
                const int b = b0 + wid * 4 + rr;
                const size_t gbase = (size_t)b * 1024 + n0 + lane * 4;
                fa[rr] = *(const float4*)(f + gbase);
                pa[rr] = *(const float4*)(pf + gbase);
            }
            float bias_v2[2];
#pragma unroll
            for (int nt = 0; nt < 2; nt++) bias_v2[nt] = b2[nb * 256 + wid * 32 + nt * 16 + r15];
            bf16x8 w2r[2][4];
#pragma unroll
            for (int nt = 0; nt < 2; nt++)
#pragma unroll
                for (int ks = 0; ks < 4; ks++)
                    w2r[nt][ks] = *(const bf16x8*)(w2_img + (size_t)((nb * 16 + wid * 2 + nt) * 4 + ks) * 512 + lane * 8);
#pragma unroll
            for (int nt = 0; nt < 2; nt++) {
#pragma unroll
                for (int mtl = 0; mtl < 2; mtl++) {
                    f32x4 cc = (f32x4){0.f, 0.f, 0.f, 0.f};
#pragma unroll
                    for (int ks = 0; ks < 4; ks++) cc = MFMA(afg[mtl][ks], w2r[nt][ks], cc);
                    const int nloc = wid * 32 + nt * 16 + r15;        // 0..255
                    const int chunk = nloc >> 5, within = nloc & 31;
#pragma unroll
                    for (int r = 0; r < 4; r++)
                        Ls[(size_t)(mtl * 16 + q * 4 + r) * 288 + chunk * 36 + within] = cc[r] + bias_v2[nt];
                }
            }
            __syncthreads();
            {   // wave-contiguous epilogue: wave w rows w*4..+4, lane i <-> n0+4i
                const float* ls = Ls + (size_t)(wid * 4) * 288 + (lane >> 3) * 36 + (lane & 7) * 4;
#pragma unroll
                for (int rr = 0; rr < 4; rr++) {
                    const int b = b0 + wid * 4 + rr;
                    const size_t gbase = (size_t)b * 1024 + n0 + lane * 4;
                    float4 lv = *(const float4*)(ls + rr * 288);
                    float4 o;
                    o.x = lv.x + fa[rr].x + pa[rr].x; o.y = lv.y + fa[rr].y + pa[rr].y;
                    o.z = lv.z + fa[rr].z + pa[rr].z; o.w = lv.w + fa[rr].w + pa[rr].w;
                    *(float4*)(out + gbase) = o;
                }
            }
            __syncthreads();   // Ls reuse protection for next nb
        }
    }
}

// ---------------- launch ----------------
extern "C" void kernel_launch(void* const* d_in, const int* in_sizes, int n_in,
                              void* d_out, int out_size, void* d_ws, size_t ws_size,
                              hipStream_t stream)
{
    const float* f    = (const float*)d_in[0];
    const float* pf   = (const float*)d_in[1];
    const float* wf   = (const float*)d_in[2];
    const float* bfb  = (const float*)d_in[3];
    const float* wpf  = (const float*)d_in[4];
    const float* bpfb = (const float*)d_in[5];
    const float* w2   = (const float*)d_in[6];
    const float* b2   = (const float*)d_in[7];
    const float* pgw  = (const float*)d_in[8];
    const float* pgb  = (const float*)d_in[9];

    char* ws = (char*)d_ws;
    ushort* pg_img = (ushort*)(ws + 0);          // 2 MB
    ushort* w_img  = (ushort*)(ws + 2097152);    // 512 KB
    ushort* w2_img = (ushort*)(ws + 2621440);    // 256 KB
    float*  out    = (float*)d_out;

    k0_convert<<<dim3(704), dim3(256), 0, stream>>>(pgw, wf, wpf, w2, pg_img, w_img, w2_img);
    mega<<<dim3(256), dim3(512), 0, stream>>>(f, pf, w_img, bfb, bpfb,
                                              pg_img, pgb, w2_img, b2, out);
}